// Round 8
// baseline (112.773 us; speedup 1.0000x reference)
//
#include <hip/hip_runtime.h>

// GaussianDynamics recurrent cell as a parallel affine scan, pipelined rows.
// x_t = S_t x_{t-1} + o_t,  S_t = I + (A - xic_t C) dt,  o_t = xic_t dy_t
// out_t = C x_{t-1} dt  (pre-update state)
//
// R8 vs R7 (98.8us, mem+VALU additive convoy):
//  - ROWS=4 rows per block, double-buffered LDS (2x16KB). Per iter: issue
//    row r+1's stage (4x global_load_lds + 2x dy dwordx4) BEFORE the counted
//    vmcnt wait for row r -> next row's HBM traffic streams under current
//    row's compute. This is the only way loads for future work exist while
//    the CU computes (8 independent blocks convoy; they don't self-overlap).
//  - Counted s_waitcnt vmcnt(N): N = #vmem ops guaranteed issued after row
//    r's stage = {6,8,8,2} for r={0,1,2,3} (stores 2/wave min + next stage 6).
//    Smaller N is always safe (drains more). dy/x0/params consumed via
//    compiler-tracked register deps (compiler adds its own waits).
//  - Raw s_barrier + lgkmcnt(0) instead of __syncthreads: __syncthreads emits
//    s_waitcnt vmcnt(0) before the barrier, which would drain the prefetch
//    and re-serialize. wsum ping-pong[2] makes one barrier per row race-free.
//  - Each wave DMAs/reads ONLY its own LDS quarter: no cross-wave staging
//    hazards, no staging barrier at all.

constexpr int BATCH = 16384;
constexpr int TLEN  = 1000;
constexpr int TPB   = 256;
constexpr int SPT   = 4;               // TPB*SPT = 1024 >= TLEN
constexpr int ROWS  = 4;               // rows per block (pipeline depth)
constexpr int NBLK  = BATCH / ROWS;    // 4096 blocks

typedef float vfloat4 __attribute__((ext_vector_type(4)));
typedef float vfloat2 __attribute__((ext_vector_type(2)));

template <int CTRL, int ROWMASK>
__device__ __forceinline__ float dppf(float oldv, float srcv) {
    return __int_as_float(__builtin_amdgcn_update_dpp(
        __float_as_int(oldv), __float_as_int(srcv), CTRL, ROWMASK, 0xf, false));
}

__global__ __launch_bounds__(TPB, 4) void gd_scan_kernel(
    const float* __restrict__ xicovs,  // [B,T,2,2]
    const float* __restrict__ dyv,     // [B,T,2]
    const float* __restrict__ cA,      // [2,2]
    const float* __restrict__ Cm,      // [2,2]
    const float* __restrict__ x0,      // [B,2]
    const float* __restrict__ dtp,     // [1]
    float* __restrict__ out)           // [B,T,2] then [B,2]
{
    __shared__ vfloat4 s_xc[2][1024];     // double-buffered AoS xicov rows
    __shared__ float wsum[2][4][6];       // ping-pong inter-wave totals

    const int tid  = threadIdx.x;
    const int lane = tid & 63;
    const int wv   = tid >> 6;
    const int row0 = blockIdx.x * ROWS;

    const int t0  = tid * SPT;
    const int t0m = (t0 <= TLEN - SPT) ? t0 : (TLEN - SPT);

    // ---- uniform params (s_load expected; drained at W0 harmlessly if vmem) ----
    const float dts = dtp[0];
    const float Cd00 = Cm[0] * dts, Cd01 = Cm[1] * dts, Cd10 = Cm[2] * dts, Cd11 = Cm[3] * dts;
    const float nCd00 = -Cd00, nCd01 = -Cd01, nCd10 = -Cd10, nCd11 = -Cd11;
    const float Ad00 = 1.f + cA[0] * dts, Ad01 = cA[1] * dts;
    const float Ad10 = cA[2] * dts,       Ad11 = 1.f + cA[3] * dts;

    // ---- x0 for the block's 4 rows (8 floats, 16B aligned) ----
    const vfloat4 x0a = *reinterpret_cast<const vfloat4*>(x0 + (size_t)row0 * 2);
    const vfloat4 x0b = *reinterpret_cast<const vfloat4*>(x0 + (size_t)row0 * 2 + 4);
    const float x0s[8] = {x0a.x, x0a.y, x0a.z, x0a.w, x0b.x, x0b.y, x0b.z, x0b.w};

    vfloat4 dyA[2], dyB[2];   // ping-pong dy prefetch (static-indexed post-unroll)

    // stage row RR into buffer BUF: 4x global_load_lds(16B) per wave into its
    // own quarter (XOR-involution pre-swizzled source), + 2x dy dwordx4 to regs
#define STAGE(BUF, RR)                                                         \
    do {                                                                       \
        const float* rowx_ = xicovs + (size_t)(RR) * (TLEN * 4);               \
        _Pragma("unroll")                                                      \
        for (int k = 0; k < 4; ++k) {                                          \
            const int pw_ = k * 64 + lane;                                     \
            const int gw_ = pw_ ^ ((pw_ >> 3) & 7);                            \
            int g_ = 256 * wv + gw_;                                           \
            if (g_ > TLEN - 1) g_ = TLEN - 1;                                  \
            __builtin_amdgcn_global_load_lds(                                  \
                (const __attribute__((address_space(1))) void*)(rowx_ + (size_t)g_ * 4),     \
                (__attribute__((address_space(3))) void*)&s_xc[BUF][wv * 256 + k * 64],      \
                16, 0, 0);                                                     \
        }                                                                      \
        const vfloat4* gd4_ = reinterpret_cast<const vfloat4*>(dyv + (size_t)(RR) * (TLEN * 2)); \
        dyA[(RR) & 1] = gd4_[t0m >> 1];                                        \
        dyB[(RR) & 1] = gd4_[(t0m >> 1) + 1];                                  \
    } while (0)

    // ---- prologue: stage row 0 ----
    STAGE(0, row0);

#pragma unroll
    for (int r = 0; r < ROWS; ++r) {
        const int row = row0 + r;
        const int buf = r & 1;

        // ---- issue next row's stage; it flies under this row's compute ----
        if (r + 1 < ROWS) STAGE((r + 1) & 1, row + 1);

        // ---- counted wait: drain row r's DMAs, keep row r+1's in flight ----
        if (r == 0)            asm volatile("s_waitcnt vmcnt(6)" ::: "memory");
        else if (r < ROWS - 1) asm volatile("s_waitcnt vmcnt(8)" ::: "memory");
        else                   asm volatile("s_waitcnt vmcnt(2)" ::: "memory");

        // ---- read own 4 timesteps (swizzled ds_read_b128) ----
        vfloat4 xc[SPT];
#pragma unroll
        for (int s = 0; s < SPT; ++s) {
            const int gw  = 4 * lane + s;
            const int pos = gw ^ ((gw >> 3) & 7);
            xc[s] = s_xc[buf][wv * 256 + pos];
        }
        const float dy0s[SPT] = {dyA[buf].x, dyA[buf].z, dyB[buf].x, dyB[buf].z};
        const float dy1s[SPT] = {dyA[buf].y, dyA[buf].w, dyB[buf].y, dyB[buf].w};

        // ---- per-step affine (S,o): S = Ad + xi*nCd, o = xi*dy; compose ----
        float S00s[SPT], S01s[SPT], S10s[SPT], S11s[SPT], o0s[SPT], o1s[SPT];
        float M00 = 1.f, M01 = 0.f, M10 = 0.f, M11 = 1.f, c0 = 0.f, c1 = 0.f;
#pragma unroll
        for (int s = 0; s < SPT; ++s) {
            const int t = t0 + s;
            const float xi00 = xc[s].x, xi01 = xc[s].y, xi10 = xc[s].z, xi11 = xc[s].w;
            float S00 = Ad00 + xi00 * nCd00 + xi01 * nCd10;
            float S01 = Ad01 + xi00 * nCd01 + xi01 * nCd11;
            float S10 = Ad10 + xi10 * nCd00 + xi11 * nCd10;
            float S11 = Ad11 + xi10 * nCd01 + xi11 * nCd11;
            float o0 = xi00 * dy0s[s] + xi01 * dy1s[s];
            float o1 = xi10 * dy0s[s] + xi11 * dy1s[s];
            if (t >= TLEN) { S00 = 1.f; S01 = 0.f; S10 = 0.f; S11 = 1.f; o0 = 0.f; o1 = 0.f; }
            S00s[s] = S00; S01s[s] = S01; S10s[s] = S10; S11s[s] = S11; o0s[s] = o0; o1s[s] = o1;
            const float n00 = S00 * M00 + S01 * M10;
            const float n01 = S00 * M01 + S01 * M11;
            const float n10 = S10 * M00 + S11 * M10;
            const float n11 = S10 * M01 + S11 * M11;
            const float nc0 = S00 * c0 + S01 * c1 + o0;
            const float nc1 = S10 * c0 + S11 * c1 + o1;
            M00 = n00; M01 = n01; M10 = n10; M11 = n11; c0 = nc0; c1 = nc1;
        }

        // ---- wave-level inclusive scan via DPP ----
#define SCAN_STEP(CTRL, RM)                                        \
        do {                                                       \
            const float m00 = dppf<CTRL, RM>(1.f, M00);            \
            const float m01 = dppf<CTRL, RM>(0.f, M01);            \
            const float m10 = dppf<CTRL, RM>(0.f, M10);            \
            const float m11 = dppf<CTRL, RM>(1.f, M11);            \
            const float lc0 = dppf<CTRL, RM>(0.f, c0);             \
            const float lc1 = dppf<CTRL, RM>(0.f, c1);             \
            const float n00 = M00 * m00 + M01 * m10;               \
            const float n01 = M00 * m01 + M01 * m11;               \
            const float n10 = M10 * m00 + M11 * m10;               \
            const float n11 = M10 * m01 + M11 * m11;               \
            const float nc0 = M00 * lc0 + M01 * lc1 + c0;          \
            const float nc1 = M10 * lc0 + M11 * lc1 + c1;          \
            M00 = n00; M01 = n01; M10 = n10; M11 = n11;            \
            c0 = nc0; c1 = nc1;                                    \
        } while (0)

        SCAN_STEP(0x111, 0xf);  // row_shr:1
        SCAN_STEP(0x112, 0xf);  // row_shr:2
        SCAN_STEP(0x114, 0xf);  // row_shr:4
        SCAN_STEP(0x118, 0xf);  // row_shr:8
        SCAN_STEP(0x142, 0xa);  // row_bcast:15 -> rows 1,3
        SCAN_STEP(0x143, 0xc);  // row_bcast:31 -> rows 2,3
#undef SCAN_STEP

        // ---- inter-wave fixup (raw barrier; prefetch stays in flight) ----
        if (lane == 63) {
            wsum[buf][wv][0] = M00; wsum[buf][wv][1] = M01;
            wsum[buf][wv][2] = M10; wsum[buf][wv][3] = M11;
            wsum[buf][wv][4] = c0;  wsum[buf][wv][5] = c1;
        }
        asm volatile("s_waitcnt lgkmcnt(0)" ::: "memory");
        __builtin_amdgcn_s_barrier();

        float P00 = 1.f, P01 = 0.f, P10 = 0.f, P11 = 1.f, Pc0 = 0.f, Pc1 = 0.f;
        for (int w = 0; w < wv; ++w) {
            const float w00 = wsum[buf][w][0], w01 = wsum[buf][w][1];
            const float w10 = wsum[buf][w][2], w11 = wsum[buf][w][3];
            const float wc0 = wsum[buf][w][4], wc1 = wsum[buf][w][5];
            const float n00 = w00 * P00 + w01 * P10;
            const float n01 = w00 * P01 + w01 * P11;
            const float n10 = w10 * P00 + w11 * P10;
            const float n11 = w10 * P01 + w11 * P11;
            const float nc0 = w00 * Pc0 + w01 * Pc1 + wc0;
            const float nc1 = w10 * Pc0 + w11 * Pc1 + wc1;
            P00 = n00; P01 = n01; P10 = n10; P11 = n11; Pc0 = nc0; Pc1 = nc1;
        }

        // ---- within-wave exclusive = inclusive of lane-1 ----
        float e00 = __shfl_up(M00, 1), e01 = __shfl_up(M01, 1);
        float e10 = __shfl_up(M10, 1), e11 = __shfl_up(M11, 1);
        float ec0 = __shfl_up(c0, 1),  ec1 = __shfl_up(c1, 1);
        if (lane == 0) { e00 = 1.f; e01 = 0.f; e10 = 0.f; e11 = 1.f; ec0 = 0.f; ec1 = 0.f; }

        // E = e o P
        const float E00 = e00 * P00 + e01 * P10;
        const float E01 = e00 * P01 + e01 * P11;
        const float E10 = e10 * P00 + e11 * P10;
        const float E11 = e10 * P01 + e11 * P11;
        const float Ec0 = e00 * Pc0 + e01 * Pc1 + ec0;
        const float Ec1 = e10 * Pc0 + e11 * Pc1 + ec1;

        // start state for this chunk: x_{t0-1} = E(x0)
        const float xa = x0s[2 * r], xb = x0s[2 * r + 1];
        float xq0 = E00 * xa + E01 * xb + Ec0;
        float xq1 = E10 * xa + E11 * xb + Ec1;

        // ---- replay chunk, emit outputs (Cd folded) ----
        float o0v[SPT], o1v[SPT];
#pragma unroll
        for (int s = 0; s < SPT; ++s) {
            o0v[s] = Cd00 * xq0 + Cd01 * xq1;
            o1v[s] = Cd10 * xq0 + Cd11 * xq1;
            const float nx0 = S00s[s] * xq0 + S01s[s] * xq1 + o0s[s];
            const float nx1 = S10s[s] * xq0 + S11s[s] * xq1 + o1s[s];
            xq0 = nx0; xq1 = nx1;
        }

        // TLEN % SPT == 0: threads with t0 < TLEN have full chunks (2 stores),
        // threads 250..255 store nothing -> wave-uniform vmem counts.
        if (t0 < TLEN) {
            float* ob = out + (size_t)row * TLEN * 2 + (size_t)t0 * 2;
            vfloat4 w0 = {o0v[0], o1v[0], o0v[1], o1v[1]};
            vfloat4 w1 = {o0v[2], o1v[2], o0v[3], o1v[3]};
            __builtin_nontemporal_store(w0, reinterpret_cast<vfloat4*>(ob));
            __builtin_nontemporal_store(w1, reinterpret_cast<vfloat4*>(ob) + 1);
        }
        if (t0 == TLEN - SPT) {
            vfloat2 xf = {xq0, xq1};
            __builtin_nontemporal_store(
                xf, reinterpret_cast<vfloat2*>(out + (size_t)BATCH * TLEN * 2 + 2 * row));
        }
    }
#undef STAGE
}

extern "C" void kernel_launch(void* const* d_in, const int* in_sizes, int n_in,
                              void* d_out, int out_size, void* d_ws, size_t ws_size,
                              hipStream_t stream) {
    const float* xicovs = (const float*)d_in[0];
    const float* dyv    = (const float*)d_in[1];
    const float* cA     = (const float*)d_in[2];
    const float* Cm     = (const float*)d_in[3];
    const float* x0     = (const float*)d_in[4];
    const float* dtp    = (const float*)d_in[5];
    float* out = (float*)d_out;

    gd_scan_kernel<<<NBLK, TPB, 0, stream>>>(xicovs, dyv, cA, Cm, x0, dtp, out);
}